// Round 1
// baseline (487.462 us; speedup 1.0000x reference)
//
#include <hip/hip_runtime.h>

// GCNConv: out = D^-1/2 (A+I) D^-1/2 X W + b
// N=100000, E=1600000, Din=Dout=128; x/W/b fp32, edge_index int32, out fp32.
//
// R5: column-sliced gather. h stored slice-major hs[8][N][16 bf16] so each
//     XCD's slice working set is 3.2 MB (< 4 MB private L2). slice =
//     blockIdx.x & 7 rides the round-robin workgroup->XCD dispatch; h
//     re-reads (410 MB logical) become L2 hits instead of HBM fetches.
//     Wave = (node, slice): 8 edge-slots x 8 col-pair lanes, 16 edges in
//     flight, shfl_xor tree reduce over slots.

#define ELEMS_PER_SCAN_BLOCK 2048  // 256 threads * 8
#define CHUNK 4096                 // edges per hist/place block

typedef __attribute__((ext_vector_type(8))) short short8;
typedef __attribute__((ext_vector_type(4))) float f32x4;

__device__ inline unsigned short f2bf(float f) {  // fp32 -> bf16 RNE
    unsigned u = __float_as_uint(f);
    u += 0x7fffu + ((u >> 16) & 1u);
    return (unsigned short)(u >> 16);
}
__device__ inline float bf_lo(unsigned u) { return __uint_as_float(u << 16); }
__device__ inline float bf_hi(unsigned u) { return __uint_as_float(u & 0xffff0000u); }

// ---- coarse histogram: LDS only ----
__global__ __launch_bounds__(256) void k_hist(const int* __restrict__ col,
                                              int* __restrict__ histg,
                                              int E, int NC, int NBLK) {
    __shared__ int lh[1024];
    int t = threadIdx.x, blk = blockIdx.x;
    for (int i = t; i < 1024; i += 256) lh[i] = 0;
    __syncthreads();
    int base = blk * CHUNK;
    #pragma unroll
    for (int i = 0; i < CHUNK / 256; ++i) {
        int e = base + i * 256 + t;
        if (e < E) atomicAdd(&lh[col[e] >> 7], 1);
    }
    __syncthreads();
    for (int b = t; b < NC; b += 256) histg[b * NBLK + blk] = lh[b];
}

// ---- scan (3 kernels) ----
__device__ inline int wave_incl_scan(int x, int lane) {
    #pragma unroll
    for (int d = 1; d < 64; d <<= 1) {
        int y = __shfl_up(x, d, 64);
        if (lane >= d) x += y;
    }
    return x;
}

__global__ void k_scan1(const int* __restrict__ in, int* __restrict__ out,
                        int* __restrict__ bsum, int M) {
    __shared__ int wsum[4];
    __shared__ int woff[4];
    int t = threadIdx.x, lane = t & 63, wid = t >> 6;
    int base = blockIdx.x * ELEMS_PER_SCAN_BLOCK + t * 8;
    int v[8];
    #pragma unroll
    for (int i = 0; i < 8; ++i) v[i] = (base + i < M) ? in[base + i] : 0;
    int run = 0;
    #pragma unroll
    for (int i = 0; i < 8; ++i) { int x = v[i]; v[i] = run; run += x; }
    int incl = wave_incl_scan(run, lane);
    int excl = incl - run;
    if (lane == 63) wsum[wid] = incl;
    __syncthreads();
    if (t == 0) {
        int r = 0;
        #pragma unroll
        for (int w = 0; w < 4; ++w) { int s = wsum[w]; woff[w] = r; r += s; }
        bsum[blockIdx.x] = r;
    }
    __syncthreads();
    int off = woff[wid] + excl;
    #pragma unroll
    for (int i = 0; i < 8; ++i)
        if (base + i < M) out[base + i] = v[i] + off;
}

__global__ void k_scan2(const int* __restrict__ bsum, int* __restrict__ boff, int NB) {
    __shared__ int wsum[4];
    __shared__ int woff[4];
    int t = threadIdx.x, lane = t & 63, wid = t >> 6;
    int x = (t < NB) ? bsum[t] : 0;
    int incl = wave_incl_scan(x, lane);
    int excl = incl - x;
    if (lane == 63) wsum[wid] = incl;
    __syncthreads();
    if (t == 0) {
        int r = 0;
        #pragma unroll
        for (int w = 0; w < 4; ++w) { int s = wsum[w]; woff[w] = r; r += s; }
    }
    __syncthreads();
    if (t < NB) boff[t] = woff[wid] + excl;
}

__global__ void k_scan3(int* __restrict__ arr, const int* __restrict__ boff, int M) {
    int t = threadIdx.x;
    int base = blockIdx.x * ELEMS_PER_SCAN_BLOCK + t * 8;
    int off = boff[blockIdx.x];
    #pragma unroll
    for (int i = 0; i < 8; ++i) {
        int idx = base + i;
        if (idx < M) arr[idx] += off;
    }
}

// ---- coarse placement: LDS cursors; payload ((c&127)<<17|row, w) ----
__global__ __launch_bounds__(256) void k_place(const int* __restrict__ row,
                                               const int* __restrict__ col,
                                               const float* __restrict__ wgt,
                                               const int* __restrict__ histg,
                                               int2* __restrict__ srw,
                                               int E, int NC, int NBLK) {
    __shared__ int lo[1024];
    int t = threadIdx.x, blk = blockIdx.x;
    for (int b = t; b < NC; b += 256) lo[b] = histg[b * NBLK + blk];
    __syncthreads();
    int base = blk * CHUNK;
    #pragma unroll
    for (int i = 0; i < CHUNK / 256; ++i) {
        int e = base + i * 256 + t;
        if (e < E) {
            int c = col[e];
            int pos = atomicAdd(&lo[c >> 7], 1);
            srw[pos] = make_int2(((c & 127) << 17) | row[e], __float_as_int(wgt[e]));
        }
    }
}

// ---- fine pass: exact CSR within each 128-node bucket + dis + spack ----
__global__ __launch_bounds__(256) void k_fine(const int* __restrict__ histg,
                                              const int2* __restrict__ srw,
                                              int* __restrict__ rowptr,
                                              float* __restrict__ dis,
                                              int2* __restrict__ spack,
                                              int E, int N, int NC, int NBLK) {
    __shared__ int cnt128[128];
    __shared__ float degf[128];
    __shared__ int cur128[128];
    __shared__ int wtot[2];
    int t = threadIdx.x, b = blockIdx.x;
    int nb = b << 7;
    int start = histg[b * NBLK];
    int end = (b == NC - 1) ? E : histg[(b + 1) * NBLK];
    if (t < 128) { cnt128[t] = 0; degf[t] = 1.0f; }  // 1.0 = self-loop weight
    __syncthreads();
    // phase 1: histogram + weighted degree
    for (int j = start + t; j < end; j += 256) {
        int2 s = srw[j];
        int c = s.x >> 17;
        atomicAdd(&cnt128[c], 1);
        atomicAdd(&degf[c], __int_as_float(s.y));
    }
    __syncthreads();
    // phase 2: 128-entry exclusive scan, write rowptr/dis, seed cursors
    int v = 0, incl = 0;
    if (t < 128) {
        v = cnt128[t];
        incl = wave_incl_scan(v, t & 63);
        if ((t & 63) == 63) wtot[t >> 6] = incl;
    }
    __syncthreads();
    if (t < 128) {
        int excl = incl - v + ((t >= 64) ? wtot[0] : 0);
        int p = start + excl;
        cur128[t] = p;
        int n = nb + t;
        if (n < N) {
            rowptr[n] = p;
            dis[n] = rsqrtf(degf[t]);
        }
    }
    if (t == 0 && b == NC - 1) rowptr[N] = E;
    __syncthreads();
    // phase 3: final placement (strip c bits -> (row, w))
    for (int j = start + t; j < end; j += 256) {
        int2 s = srw[j];
        int c = s.x >> 17;
        int pos = atomicAdd(&cur128[c], 1);
        spack[pos] = make_int2(s.x & 0x1FFFF, s.y);
    }
}

// ---- W transpose + bf16 convert ----
__global__ void k_wprep(const float* __restrict__ W, unsigned short* __restrict__ Wtg) {
    int n = blockIdx.x;
    int k = threadIdx.x;
    Wtg[n * 128 + k] = f2bf(W[k * 128 + n]);
}

// ---- h = x @ W, bf16 MFMA 16x16x32. 64 rows x 128 cols / block, 4 waves.
//      Output SLICE-MAJOR: hs[s][n][16] bf16, s = col/16. ----
__global__ __launch_bounds__(256) void k_gemm(const float* __restrict__ x,
                                              const unsigned short* __restrict__ Wtg,
                                              unsigned short* __restrict__ h, int N) {
    __shared__ short Xs[64][136];
    __shared__ short Ws[128][136];
    int t = threadIdx.x;
    int lane = t & 63, wid = t >> 6;
    int row0 = blockIdx.x * 64;
    {
        int r = t >> 2;
        int kseg = (t & 3) * 32;
        int gr = row0 + r;
        const float4* src = (const float4*)(x + (size_t)gr * 128 + kseg);
        #pragma unroll
        for (int i = 0; i < 4; ++i) {
            float4 v0 = make_float4(0.f, 0.f, 0.f, 0.f), v1 = v0;
            if (gr < N) { v0 = src[2 * i]; v1 = src[2 * i + 1]; }
            short8 p;
            p[0] = (short)f2bf(v0.x); p[1] = (short)f2bf(v0.y);
            p[2] = (short)f2bf(v0.z); p[3] = (short)f2bf(v0.w);
            p[4] = (short)f2bf(v1.x); p[5] = (short)f2bf(v1.y);
            p[6] = (short)f2bf(v1.z); p[7] = (short)f2bf(v1.w);
            *(short8*)&Xs[r][kseg + 8 * i] = p;
        }
    }
    {
        int n = t >> 1;
        int seg = (t & 1) * 64;
        const short* wsrc = (const short*)Wtg + n * 128 + seg;
        #pragma unroll
        for (int i = 0; i < 8; ++i)
            *(short8*)&Ws[n][seg + 8 * i] = *(const short8*)(wsrc + 8 * i);
    }
    __syncthreads();

    int q = lane >> 4;
    int m = lane & 15;
    f32x4 acc[8];
    #pragma unroll
    for (int tde = 0; tde < 8; ++tde) acc[tde] = (f32x4){0.f, 0.f, 0.f, 0.f};
    #pragma unroll
    for (int kc = 0; kc < 128; kc += 32) {
        short8 af = *(const short8*)&Xs[wid * 16 + m][kc + q * 8];
        #pragma unroll
        for (int tde = 0; tde < 8; ++tde) {
            short8 bf = *(const short8*)&Ws[tde * 16 + m][kc + q * 8];
            acc[tde] = __builtin_amdgcn_mfma_f32_16x16x32_bf16(af, bf, acc[tde], 0, 0, 0);
        }
    }
    #pragma unroll
    for (int r = 0; r < 4; ++r) {
        int grow = row0 + wid * 16 + q * 4 + r;
        if (grow < N) {
            #pragma unroll
            for (int tde = 0; tde < 8; ++tde)
                h[((size_t)tde * N + grow) * 16 + m] = f2bf(acc[tde][r]);
        }
    }
}

// ---- gather v4 (R5): column-sliced. Wave = (node, slice of 16 cols).
//      slice = blockIdx.x & 7 -> rides round-robin block->XCD dispatch so
//      each XCD's h-slice (3.2 MB) stays L2-resident.
//      Lane layout: slot = lane>>3 (edge slot 0..7), cp = lane&7 (col pair).
//      16 edges in flight (2 chains); shfl_xor tree-reduce over slots. ----
__global__ __launch_bounds__(256) void k_gather(const unsigned int* __restrict__ hs,
                                                const float* __restrict__ dis,
                                                const int* __restrict__ rowptr,
                                                const long* __restrict__ spackl,
                                                const float* __restrict__ bias,
                                                float* __restrict__ out, int N) {
    int t = threadIdx.x;
    int lane = t & 63, wid = t >> 6;
    int s = blockIdx.x & 7;
    int node = (blockIdx.x >> 3) * 4 + wid;
    if (node >= N) return;
    int slot = lane >> 3;
    int cp = lane & 7;
    const unsigned int* hsl = hs + (size_t)s * N * 8;  // slice base, u32 view

    float dn = dis[node];
    int jb = rowptr[node], je = rowptr[node + 1];
    float2 acc = make_float2(0.f, 0.f);

    for (int j0 = jb; j0 < je; j0 += 16) {
        int e0 = j0 + slot;
        int e1 = e0 + 8;
        int c0 = (e0 < je) ? e0 : je - 1;
        int c1 = (e1 < je) ? e1 : je - 1;
        long q0 = spackl[c0];
        long q1 = spackl[c1];
        int r0 = (int)q0 & 0x1FFFF;
        int r1 = (int)q1 & 0x1FFFF;
        float w0 = __uint_as_float((unsigned)((unsigned long)q0 >> 32));
        float w1 = __uint_as_float((unsigned)((unsigned long)q1 >> 32));
        float a0 = (e0 < je) ? dis[r0] * w0 : 0.f;
        float a1 = (e1 < je) ? dis[r1] * w1 : 0.f;
        unsigned v0 = hsl[(size_t)r0 * 8 + cp];
        unsigned v1 = hsl[(size_t)r1 * 8 + cp];
        acc.x = fmaf(a0, bf_lo(v0), acc.x);
        acc.y = fmaf(a0, bf_hi(v0), acc.y);
        acc.x = fmaf(a1, bf_lo(v1), acc.x);
        acc.y = fmaf(a1, bf_hi(v1), acc.y);
    }

    // reduce partial sums across the 8 edge slots (lane bits 3,4,5)
    #pragma unroll
    for (int d = 8; d < 64; d <<= 1) {
        acc.x += __shfl_xor(acc.x, d, 64);
        acc.y += __shfl_xor(acc.y, d, 64);
    }

    // self-loop term + epilogue; slot-0 lanes write one 64B line per node
    unsigned vs = hsl[(size_t)node * 8 + cp];
    float tx = acc.x + dn * bf_lo(vs);
    float ty = acc.y + dn * bf_hi(vs);
    if (slot == 0) {
        int col0 = s * 16 + cp * 2;
        float2 bv = *(const float2*)(bias + col0);
        float2 o;
        o.x = bv.x + dn * tx;
        o.y = bv.y + dn * ty;
        union { float2 f; double d; } cvt;
        cvt.f = o;
        __builtin_nontemporal_store(cvt.d, (double*)(out + (size_t)node * 128 + col0));
    }
}

extern "C" void kernel_launch(void* const* d_in, const int* in_sizes, int n_in,
                              void* d_out, int out_size, void* d_ws, size_t ws_size,
                              hipStream_t stream) {
    const float* x     = (const float*)d_in[0];
    const int*   eidx  = (const int*)d_in[1];   // [2,E] int32
    const float* eattr = (const float*)d_in[2];
    const float* W     = (const float*)d_in[3];
    const float* bias  = (const float*)d_in[4];
    int N = in_sizes[0] / 128;
    int E = in_sizes[2];
    const int* row = eidx;
    const int* col = eidx + E;

    int NC = (N + 127) >> 7;                       // 782 coarse buckets
    int NBLK = (E + CHUNK - 1) / CHUNK;            // 391 hist/place blocks

    char* p = (char*)d_ws;
    auto carve = [&](size_t bytes) {
        char* q = p;
        p += (bytes + 255) & ~(size_t)255;
        return q;
    };
    unsigned short* h   = (unsigned short*)carve((size_t)N * 128 * sizeof(unsigned short));
    unsigned short* Wtg = (unsigned short*)carve(128 * 128 * sizeof(unsigned short));
    float* dis    = (float*)carve((size_t)N * sizeof(float));
    int*   rowptr = (int*)carve((size_t)(N + 1) * sizeof(int));
    int*   histg  = (int*)carve((size_t)NC * NBLK * sizeof(int));
    int2*  srw    = (int2*)carve((size_t)E * sizeof(int2));
    int2*  spack  = (int2*)carve((size_t)E * sizeof(int2));
    int*   bsum   = (int*)carve(256 * sizeof(int));
    int*   boff   = (int*)carve(256 * sizeof(int));

    int M = NC * NBLK;
    int NBs = (M + ELEMS_PER_SCAN_BLOCK - 1) / ELEMS_PER_SCAN_BLOCK;

    k_hist<<<NBLK, 256, 0, stream>>>(col, histg, E, NC, NBLK);
    k_scan1<<<NBs, 256, 0, stream>>>(histg, histg, bsum, M);
    k_scan2<<<1, 256, 0, stream>>>(bsum, boff, NBs);
    k_scan3<<<NBs, 256, 0, stream>>>(histg, boff, M);
    k_place<<<NBLK, 256, 0, stream>>>(row, col, eattr, histg, srw, E, NC, NBLK);
    k_fine<<<NC, 256, 0, stream>>>(histg, srw, rowptr, dis, spack, E, N, NC, NBLK);
    k_wprep<<<128, 128, 0, stream>>>(W, Wtg);
    k_gemm<<<(N + 63) / 64, 256, 0, stream>>>(x, Wtg, h, N);
    {
        int blocks = ((N + 3) >> 2) * 8;  // (node-group) x 8 slices
        k_gather<<<blocks, 256, 0, stream>>>((const unsigned int*)h, dis, rowptr,
                                             (const long*)spack, bias, (float*)d_out, N);
    }
}